// Round 10
// baseline (1887.734 us; speedup 1.0000x reference)
//
#include <hip/hip_runtime.h>
#include <math.h>

typedef __attribute__((ext_vector_type(4))) float f32x4;
typedef __attribute__((ext_vector_type(8))) short s16x8;

__device__ __forceinline__ unsigned short f2bf(float f){
  union { float f; unsigned u; } v; v.f = f;
  return (unsigned short)((v.u + 0x7fffu + ((v.u >> 16) & 1u)) >> 16);
}
__device__ __forceinline__ float bf2f(unsigned short h){
  union { unsigned u; float f; } v; v.u = ((unsigned)h) << 16;
  return v.f;
}
// split v into hi (truncated bf16) + lo (rounded bf16 of remainder); hi+lo ~ v (rel err ~2^-16)
struct HL { short hi, lo; };
__device__ __forceinline__ HL split2(float v){
  union { float f; unsigned u; } c; c.f = v;
  unsigned short h = (unsigned short)(c.u >> 16);
  HL r; r.hi = (short)h; r.lo = (short)f2bf(v - bf2f(h));
  return r;
}
__device__ __forceinline__ void mk8(const f32x4& v0, const f32x4& v1, s16x8& hi, s16x8& lo){
  HL h;
  h = split2(v0.x); hi[0]=h.hi; lo[0]=h.lo;
  h = split2(v0.y); hi[1]=h.hi; lo[1]=h.lo;
  h = split2(v0.z); hi[2]=h.hi; lo[2]=h.lo;
  h = split2(v0.w); hi[3]=h.hi; lo[3]=h.lo;
  h = split2(v1.x); hi[4]=h.hi; lo[4]=h.lo;
  h = split2(v1.y); hi[5]=h.hi; lo[5]=h.lo;
  h = split2(v1.z); hi[6]=h.hi; lo[6]=h.lo;
  h = split2(v1.w); hi[7]=h.hi; lo[7]=h.lo;
}
__device__ __forceinline__ void mk8r(const f32x4& v0, const f32x4& v1, s16x8& hi){
  hi[0]=(short)f2bf(v0.x); hi[1]=(short)f2bf(v0.y);
  hi[2]=(short)f2bf(v0.z); hi[3]=(short)f2bf(v0.w);
  hi[4]=(short)f2bf(v1.x); hi[5]=(short)f2bf(v1.y);
  hi[6]=(short)f2bf(v1.z); hi[7]=(short)f2bf(v1.w);
}

// ---------------------------------------------------------------------------
// Split-bf16 MFMA GEMM, reg-double-buffered, optional split-K.
// NMFMA=3: fp32-accurate (hi/lo planes, 3 MFMA). NMFMA=1: rounded bf16, 1 MFMA
// (only for GEMMs with no routing decision downstream).
// SMAX: fused row-softmax on A (requires: full K in one block i.e. kspl==1,
//       grid.y==1 so each block sees whole rows, f32 A). A is read in a
//       prepass for per-row max/sum; staging applies p=exp(v-m)*inv.
// Conflict-free kg-major LDS layout (granule (row,kg) at (row>>4)*512+kg*128+(row&15)*8).
//   z decomposes as (e, s): e = z/kspl, s = z%kspl; k-range = [s*K, (s+1)*K)
//   A row ptr = Ap + (gm/rdiv)*rs1 + (gm%rdiv)*rs2 + e*zsa + s*K + k
//   B (BT=0)  = Bp + e*zsb + (s*K + k)*ldb + gn
//   B (BT=1)  = Bp + e*zsb + gn*ldb + s*K + k
//   C index   = e*zsc + s*zscs + gm*ldc + gn
// EPI bits: 1=bias  2=+resid  4=gelu(exact)
// QKV3: e in {0,1,2} selects (Bp,bias)/(Bp1,bias1)/(Bp2,bias2)
// rowlim: per-e row count; blocks with blockM >= rowlim[e] exit (sparse MoE).
// ---------------------------------------------------------------------------
template<int BM, int BN, bool BT, int EPI, bool QKV3, int NMFMA, bool SMAX = false>
__global__ __launch_bounds__(256)
void gemm_k(const float* __restrict__ Ap, const float* __restrict__ Bp,
            const float* __restrict__ Bp1, const float* __restrict__ Bp2,
            const float* __restrict__ bias, const float* __restrict__ bias1,
            const float* __restrict__ bias2,
            const float* __restrict__ resid, float* __restrict__ Cp,
            int K, int ldb, int ldc,
            int rdiv, long rs1, long rs2, long zsa, long zsb, long zsc, int zbias,
            float alpha, const int* __restrict__ rowlim, int kspl, long zscs)
{
  const int z = blockIdx.z;
  const int e = z / kspl, sps = z - e*kspl;
  const long kbeg = (long)sps * K;
  if (rowlim && (long)blockIdx.y * BM >= (long)rowlim[e]) return;

  const float* Bsel = Bp; const float* bsel = bias;
  if constexpr (QKV3){
    if (e == 1){ Bsel = Bp1; bsel = bias1; }
    else if (e == 2){ Bsel = Bp2; bsel = bias2; }
  }

  constexpr int NGA = BM/64;
  constexpr int NGB = BN/64;
  constexpr int LOG2BN = (BN == 128 ? 7 : 6);
  constexpr int PL = (NMFMA == 3 ? 2 : 1);

  __shared__ short As[PL][BM*32];
  __shared__ short Bs[PL][BN*32];

  const int tid  = threadIdx.x;
  const int lane = tid & 63;
  const int wid  = tid >> 6;
  const int wr   = wid >> 1, wc = wid & 1;
  constexpr int WM = BM/2, WN = BN/2;
  constexpr int MR = WM/16, NR = WN/16;

  const long blockM = (long)blockIdx.y * BM;
  const long blockN = (long)blockIdx.x * BN;

  long aoffG[NGA]; int aoffL[NGA]; int arow[NGA];
#pragma unroll
  for (int i = 0; i < NGA; ++i){
    int g = i*256 + tid;
    int row = g >> 2, kg = g & 3;
    long gm = blockM + row;
    aoffG[i] = (gm / rdiv) * rs1 + (gm % rdiv) * rs2 + (long)e * zsa + kbeg + kg*8;
    aoffL[i] = (row >> 4)*512 + kg*128 + (row & 15)*8;
    arow[i] = row;
  }
  long boffG[NGB]; int boffL[NGB]; int bkg[NGB];
#pragma unroll
  for (int i = 0; i < NGB; ++i){
    int g = i*256 + tid;
    if constexpr (BT){
      int row = g >> 2, kg = g & 3;
      boffG[i] = (long)e * zsb + (blockN + row) * (long)ldb + kbeg + kg*8;
      boffL[i] = (row >> 4)*512 + kg*128 + (row & 15)*8;
      bkg[i] = 0;
    } else {
      int n = g & (BN-1), kg = g >> LOG2BN;
      boffG[i] = (long)e * zsb + blockN + n;
      bkg[i] = kg;
      boffL[i] = (n >> 4)*512 + kg*128 + (n & 15)*8;
    }
  }

  // ---- SMAX prepass: per-row max & sum(exp) over full K (BM=64 rows) ----
  __shared__ float sm_m[SMAX ? BM : 1];
  __shared__ float sm_inv[SMAX ? BM : 1];
  if constexpr (SMAX){
    __shared__ float rmx[4][BM];
    __shared__ float rsm[4][BM];
    static_assert(BM == 64, "SMAX assumes BM==64");
    int row = tid & 63, qd = tid >> 6;          // 4 threads per row
    long gm = blockM + row;
    const float* ap = Ap + (gm / rdiv) * rs1 + (gm % rdiv) * rs2 + (long)e * zsa;
    int seg = K >> 2;                           // elems per quarter
    const float* p0 = ap + qd * seg;
    float mx = -3.0e38f;
    for (int j = 0; j < seg; j += 4){
      f32x4 v = *(const f32x4*)(p0 + j);
      mx = fmaxf(mx, fmaxf(fmaxf(v.x, v.y), fmaxf(v.z, v.w)));
    }
    float sm = 0.f;
    for (int j = 0; j < seg; j += 4){
      f32x4 v = *(const f32x4*)(p0 + j);
      sm += expf(v.x - mx) + expf(v.y - mx) + expf(v.z - mx) + expf(v.w - mx);
    }
    rmx[qd][row] = mx; rsm[qd][row] = sm;
    __syncthreads();
    if (tid < 64){
      float M = fmaxf(fmaxf(rmx[0][tid], rmx[1][tid]), fmaxf(rmx[2][tid], rmx[3][tid]));
      float S = rsm[0][tid]*expf(rmx[0][tid]-M) + rsm[1][tid]*expf(rmx[1][tid]-M)
              + rsm[2][tid]*expf(rmx[2][tid]-M) + rsm[3][tid]*expf(rmx[3][tid]-M);
      sm_m[tid] = M; sm_inv[tid] = 1.0f / S;
    }
    __syncthreads();
  }

  f32x4 acc[MR][NR];
#pragma unroll
  for (int m = 0; m < MR; ++m)
#pragma unroll
    for (int n = 0; n < NR; ++n)
      acc[m][n] = (f32x4){0.f, 0.f, 0.f, 0.f};

  const int lrow = lane & 15;
  const int kg   = lane >> 4;

  auto loadA = [&](int kk, f32x4 (*a)[2]){
#pragma unroll
    for (int i = 0; i < NGA; ++i){
      a[i][0] = *(const f32x4*)(Ap + aoffG[i] + kk);
      a[i][1] = *(const f32x4*)(Ap + aoffG[i] + kk + 4);
    }
  };
  auto loadB = [&](int kk, f32x4 (*b)[2]){
#pragma unroll
    for (int i = 0; i < NGB; ++i){
      if constexpr (BT){
        b[i][0] = *(const f32x4*)(Bsel + boffG[i] + kk);
        b[i][1] = *(const f32x4*)(Bsel + boffG[i] + kk + 4);
      } else {
        long kb = kbeg + kk + bkg[i]*8;
#pragma unroll
        for (int j = 0; j < 4; ++j){
          b[i][0][j] = Bsel[boffG[i] + (kb + j)     * (long)ldb];
          b[i][1][j] = Bsel[boffG[i] + (kb + 4 + j) * (long)ldb];
        }
      }
    }
  };
  auto process = [&](f32x4 (*a)[2], f32x4 (*b)[2]){
    __syncthreads();
#pragma unroll
    for (int i = 0; i < NGA; ++i){
      f32x4 v0 = a[i][0], v1 = a[i][1];
      if constexpr (SMAX){
        float m = sm_m[arow[i]], inv = sm_inv[arow[i]];
        v0.x = expf(v0.x - m)*inv; v0.y = expf(v0.y - m)*inv;
        v0.z = expf(v0.z - m)*inv; v0.w = expf(v0.w - m)*inv;
        v1.x = expf(v1.x - m)*inv; v1.y = expf(v1.y - m)*inv;
        v1.z = expf(v1.z - m)*inv; v1.w = expf(v1.w - m)*inv;
      }
      if constexpr (NMFMA == 3){
        s16x8 hi, lo; mk8(v0, v1, hi, lo);
        *(s16x8*)&As[0][aoffL[i]] = hi;
        *(s16x8*)&As[1][aoffL[i]] = lo;
      } else {
        s16x8 hi; mk8r(v0, v1, hi);
        *(s16x8*)&As[0][aoffL[i]] = hi;
      }
    }
#pragma unroll
    for (int i = 0; i < NGB; ++i){
      if constexpr (NMFMA == 3){
        s16x8 hi, lo; mk8(b[i][0], b[i][1], hi, lo);
        *(s16x8*)&Bs[0][boffL[i]] = hi;
        *(s16x8*)&Bs[1][boffL[i]] = lo;
      } else {
        s16x8 hi; mk8r(b[i][0], b[i][1], hi);
        *(s16x8*)&Bs[0][boffL[i]] = hi;
      }
    }
    __syncthreads();

    s16x8 afh[MR], afl[MR], bfh[NR], bfl[NR];
#pragma unroll
    for (int m = 0; m < MR; ++m){
      int off = (wr*MR + m)*512 + kg*128 + lrow*8;
      afh[m] = *(const s16x8*)&As[0][off];
      if constexpr (NMFMA == 3) afl[m] = *(const s16x8*)&As[1][off];
    }
#pragma unroll
    for (int n = 0; n < NR; ++n){
      int off = (wc*NR + n)*512 + kg*128 + lrow*8;
      bfh[n] = *(const s16x8*)&Bs[0][off];
      if constexpr (NMFMA == 3) bfl[n] = *(const s16x8*)&Bs[1][off];
    }
#pragma unroll
    for (int m = 0; m < MR; ++m)
#pragma unroll
      for (int n = 0; n < NR; ++n){
        acc[m][n] = __builtin_amdgcn_mfma_f32_16x16x32_bf16(afh[m], bfh[n], acc[m][n], 0, 0, 0);
        if constexpr (NMFMA == 3){
          acc[m][n] = __builtin_amdgcn_mfma_f32_16x16x32_bf16(afl[m], bfh[n], acc[m][n], 0, 0, 0);
          acc[m][n] = __builtin_amdgcn_mfma_f32_16x16x32_bf16(afh[m], bfl[n], acc[m][n], 0, 0, 0);
        }
      }
  };

  f32x4 a0[NGA][2], a1[NGA][2], b0[NGB][2], b1[NGB][2];
  loadA(0, a0); loadB(0, b0);
  for (int k0 = 0; k0 < K; k0 += 64){
    loadA(k0 + 32, a1); loadB(k0 + 32, b1);
    process(a0, b0);
    if (k0 + 64 < K){ loadA(k0 + 64, a0); loadB(k0 + 64, b0); }
    process(a1, b1);
  }

#pragma unroll
  for (int n = 0; n < NR; ++n){
    long gn = blockN + wc*WN + n*16 + lrow;
    float bv = 0.f;
    if constexpr ((EPI & 1) != 0) bv = bsel[(long)e * zbias + gn];
#pragma unroll
    for (int m = 0; m < MR; ++m){
#pragma unroll
      for (int j = 0; j < 4; ++j){
        long gm = blockM + wr*WM + m*16 + kg*4 + j;
        long cidx = (long)e * zsc + sps * zscs + gm * (long)ldc + gn;
        float v = acc[m][n][j] * alpha + bv;
        if constexpr ((EPI & 2) != 0) v += resid[cidx];
        if constexpr ((EPI & 4) != 0) v = 0.5f * v * (1.0f + erff(v * 0.70710678f));
        Cp[cidx] = v;
      }
    }
  }
}

// ---------------- embedding: x[b,0]=bos, x[b,1+r]=emb_tables[r, ids[b,r]] ----
__global__ __launch_bounds__(256)
void embed_k(const int* __restrict__ ids, const float* __restrict__ embt,
             const float* __restrict__ bos, float* __restrict__ x)
{
  int t = blockIdx.x;
  int b = t >> 2, q = t & 3;
  const float* src;
  if (q == 0) src = bos;
  else {
    int r = q - 1;
    long id = ids[b*3 + r];
    src = embt + ((long)r * 8192 + id) * 1024;
  }
  f32x4 v = *(const f32x4*)(src + threadIdx.x * 4);
  *(f32x4*)(x + (long)t * 1024 + threadIdx.x * 4) = v;
}

// ---------------- tiny causal self-attn over T=4 ----------------
__global__ __launch_bounds__(64)
void sattn_k(const float* __restrict__ Q, const float* __restrict__ Kk,
             const float* __restrict__ V, float* __restrict__ O)
{
  int tid = blockIdx.x * 64 + threadIdx.x;
  int q = tid & 3, h = (tid >> 2) & 15;
  long b = tid >> 6;
  long t = b*4 + q;
  const float* qp = Q + t*1024 + h*64;
  float s[4]; float mx = -1e30f;
  for (int k = 0; k <= q; ++k){
    const float* kp = Kk + (b*4 + k)*1024 + h*64;
    float a = 0.f;
#pragma unroll
    for (int d = 0; d < 64; ++d) a += qp[d] * kp[d];
    s[k] = a * 0.125f; mx = fmaxf(mx, s[k]);
  }
  float den = 0.f;
  for (int k = 0; k <= q; ++k){ s[k] = expf(s[k] - mx); den += s[k]; }
  float inv = 1.f / den;
  float* op = O + t*1024 + h*64;
  for (int d = 0; d < 64; ++d){
    float a = 0.f;
    for (int k = 0; k <= q; ++k) a += s[k] * V[(b*4 + k)*1024 + h*64 + d];
    op[d] = a * inv;
  }
}

// ---------------- LayerNorm (optionally zeroes an 8-int counter array) -------
__global__ __launch_bounds__(256)
void ln_k(const float* __restrict__ in, const float* __restrict__ g,
          const float* __restrict__ b, float* __restrict__ out,
          int* __restrict__ zero8)
{
  __shared__ float red[8];
  long row = blockIdx.x;
  int tid = threadIdx.x, lane = tid & 63, wid = tid >> 6;
  if (zero8 && blockIdx.x == 0 && tid < 8) zero8[tid] = 0;
  f32x4 v = ((const f32x4*)(in + row*1024))[tid];
  float s  = v.x + v.y + v.z + v.w;
  float s2 = v.x*v.x + v.y*v.y + v.z*v.z + v.w*v.w;
  for (int o = 32; o; o >>= 1){ s += __shfl_down(s, o); s2 += __shfl_down(s2, o); }
  if (!lane){ red[wid] = s; red[4 + wid] = s2; }
  __syncthreads();
  if (tid == 0){
    float S = red[0]+red[1]+red[2]+red[3], S2 = red[4]+red[5]+red[6]+red[7];
    float m = S * (1.f/1024.f);
    float var = S2 * (1.f/1024.f) - m*m;
    red[0] = m; red[1] = 1.0f / sqrtf(var + 1e-5f);
  }
  __syncthreads();
  float m = red[0], r = red[1];
  f32x4 gv = ((const f32x4*)g)[tid], bv = ((const f32x4*)b)[tid];
  f32x4 o;
  o.x = (v.x - m)*r*gv.x + bv.x; o.y = (v.y - m)*r*gv.y + bv.y;
  o.z = (v.z - m)*r*gv.z + bv.z; o.w = (v.w - m)*r*gv.w + bv.w;
  ((f32x4*)(out + row*1024))[tid] = o;
}

// ------ MoE combine: sum 4 split-K partials + expert bias, gate, resid, LN ----
__global__ __launch_bounds__(256)
void moe_ln_k(const float* __restrict__ x, const float* __restrict__ Yg4,
              const float* __restrict__ gwp, const int* __restrict__ sg,
              const float* __restrict__ b2,
              const float* __restrict__ g, const float* __restrict__ b,
              float* __restrict__ out)
{
  __shared__ float red[8];
  long t = blockIdx.x;
  int tid = threadIdx.x, lane = tid & 63, wid = tid >> 6;
  float w0 = gwp[t*2], w1 = gwp[t*2 + 1];
  long r0 = sg[t*2], r1 = sg[t*2 + 1];
  long e0 = r0 >> 10, e1 = r1 >> 10;
  const long SP = 8388608;
  f32x4 y0 = ((const f32x4*)(Yg4 + 0*SP + r0*1024))[tid];
  f32x4 y1 = ((const f32x4*)(Yg4 + 0*SP + r1*1024))[tid];
#pragma unroll
  for (int s = 1; s < 4; ++s){
    y0 = y0 + ((const f32x4*)(Yg4 + s*SP + r0*1024))[tid];
    y1 = y1 + ((const f32x4*)(Yg4 + s*SP + r1*1024))[tid];
  }
  y0 = y0 + ((const f32x4*)(b2 + e0*1024))[tid];
  y1 = y1 + ((const f32x4*)(b2 + e1*1024))[tid];
  f32x4 v = ((const f32x4*)(x + t*1024))[tid];
  v = v + y0*w0 + y1*w1;
  float s  = v.x + v.y + v.z + v.w;
  float s2 = v.x*v.x + v.y*v.y + v.z*v.z + v.w*v.w;
  for (int o = 32; o; o >>= 1){ s += __shfl_down(s, o); s2 += __shfl_down(s2, o); }
  if (!lane){ red[wid] = s; red[4 + wid] = s2; }
  __syncthreads();
  if (tid == 0){
    float S = red[0]+red[1]+red[2]+red[3], S2 = red[4]+red[5]+red[6]+red[7];
    float m = S * (1.f/1024.f);
    float var = S2 * (1.f/1024.f) - m*m;
    red[0] = m; red[1] = 1.0f / sqrtf(var + 1e-5f);
  }
  __syncthreads();
  float m = red[0], r = red[1];
  f32x4 gv = ((const f32x4*)g)[tid], bv = ((const f32x4*)b)[tid];
  f32x4 o;
  o.x = (v.x - m)*r*gv.x + bv.x; o.y = (v.y - m)*r*gv.y + bv.y;
  o.z = (v.z - m)*r*gv.z + bv.z; o.w = (v.w - m)*r*gv.w + bv.w;
  ((f32x4*)(out + t*1024))[tid] = o;
}

// ---------------- fused router + scatter + gather ----------------
__global__ __launch_bounds__(64)
void router_gather_k(const float* __restrict__ x, const float* __restrict__ rw,
                     const float* __restrict__ rb, int* __restrict__ cnt,
                     float* __restrict__ gw, int* __restrict__ sg,
                     float* __restrict__ xg)
{
  long t = blockIdx.x;
  int lane = threadIdx.x;
  __shared__ int ssl[2];
  float acc[8] = {0,0,0,0,0,0,0,0};
  const float* xp = x + t*1024;
  for (int i = 0; i < 16; ++i){
    float xv = xp[lane + i*64];
    const float* w = rw + (long)(lane + i*64) * 8;
#pragma unroll
    for (int e = 0; e < 8; ++e) acc[e] += xv * w[e];
  }
#pragma unroll
  for (int e = 0; e < 8; ++e)
    for (int o = 32; o; o >>= 1) acc[e] += __shfl_down(acc[e], o);
  if (lane == 0){
    float lg[8]; float mx = -1e30f;
#pragma unroll
    for (int e = 0; e < 8; ++e){ lg[e] = acc[e] + rb[e]; mx = fmaxf(mx, lg[e]); }
    float ssum = 0.f;
#pragma unroll
    for (int e = 0; e < 8; ++e){ lg[e] = expf(lg[e] - mx); ssum += lg[e]; }
    float inv = 1.f / ssum;
#pragma unroll
    for (int e = 0; e < 8; ++e) lg[e] *= inv;
    int i0 = 0; float p0 = lg[0];
#pragma unroll
    for (int e = 1; e < 8; ++e) if (lg[e] > p0){ p0 = lg[e]; i0 = e; }
    int i1 = -1; float p1 = -1e30f;
#pragma unroll
    for (int e = 0; e < 8; ++e) if (e != i0 && lg[e] > p1){ p1 = lg[e]; i1 = e; }
    float w0 = 1.f / (1.f + expf(p1 - p0));
    int s0 = atomicAdd(&cnt[i0], 1);
    int s1 = atomicAdd(&cnt[i1], 1);
    int r0 = i0*1024 + s0, r1 = i1*1024 + s1;
    gw[t*2] = w0; gw[t*2 + 1] = 1.f - w0;
    sg[t*2] = r0; sg[t*2 + 1] = r1;
    ssl[0] = r0; ssl[1] = r1;
  }
  __syncthreads();
  const f32x4* xp4 = (const f32x4*)(x + t*1024);
#pragma unroll
  for (int r = 0; r < 2; ++r){
    f32x4* dp = (f32x4*)(xg + (long)ssl[r]*1024);
#pragma unroll
    for (int i = 0; i < 4; ++i) dp[lane + i*64] = xp4[lane + i*64];
  }
}

// ===========================================================================
extern "C" void kernel_launch(void* const* d_in, const int* in_sizes, int n_in,
                              void* d_out, int out_size, void* d_ws, size_t ws_size,
                              hipStream_t stream)
{
  (void)in_sizes; (void)n_in; (void)out_size; (void)ws_size;
  const int*   sem  = (const int*)  d_in[0];
  const float* enc  = (const float*)d_in[1];
  const float* embt = (const float*)d_in[2];
  const float* bos  = (const float*)d_in[3];
  const float* sa_wq = (const float*)d_in[4];  const float* sa_bq = (const float*)d_in[5];
  const float* sa_wk = (const float*)d_in[6];  const float* sa_bk = (const float*)d_in[7];
  const float* sa_wv = (const float*)d_in[8];  const float* sa_bv = (const float*)d_in[9];
  const float* sa_wo = (const float*)d_in[10]; const float* sa_bo = (const float*)d_in[11];
  const float* ca_wq = (const float*)d_in[12]; const float* ca_bq = (const float*)d_in[13];
  const float* ca_wk = (const float*)d_in[14]; /* ca_bk d_in[15]: softmax-invariant, dropped */
  const float* ca_wv = (const float*)d_in[16]; const float* ca_bv = (const float*)d_in[17];
  const float* ca_wo = (const float*)d_in[18]; const float* ca_bo = (const float*)d_in[19];
  const float* rw_   = (const float*)d_in[20]; const float* rb_   = (const float*)d_in[21];
  const float* w1_   = (const float*)d_in[22]; const float* b1_   = (const float*)d_in[23];
  const float* w2_   = (const float*)d_in[24]; const float* b2_   = (const float*)d_in[25];
  const float* ln1g = (const float*)d_in[26];  const float* ln1b = (const float*)d_in[27];
  const float* ln2g = (const float*)d_in[28];  const float* ln2b = (const float*)d_in[29];
  const float* ln3g = (const float*)d_in[30];  const float* ln3b = (const float*)d_in[31];
  const float* lnfg = (const float*)d_in[32];  const float* lnfb = (const float*)d_in[33];
  const float* outw = (const float*)d_in[34];  const float* outb = (const float*)d_in[35];
  float* logits = (float*)d_out;

  // ---- workspace carve (floats). head 6M + big 72M ~= 312 MiB ----
  float* ws = (float*)d_ws;
  const long M1 = 1l << 20;
  float* x   = ws;
  float* Qb  = ws + 1*M1;
  float* Kb  = ws + 2*M1;
  float* Vb  = ws + 3*M1;
  float* Ob  = ws + 4*M1;
  float* tmp = ws + 5*M1;
  float* gw  = ws + 6*M1;
  int*   cnt = (int*)(ws + 6*M1 + 4096);
  int*   sg  = (int*)(ws + 6*M1 + 4352);
  float* big = ws + 6*M1 + 8192;
  // cross-attn phase:
  float* Aca = big;              // [16][1024][1024] f32 (16M)
  float* S   = big + 16*M1;      // [256][64][512]   f32 (8M); raw scores (softmax fused in PV)
  float* Op  = big;              // [256][64][1024]  f32 (16M) — reuses Aca (dead)
  // MoE phase (CA region dead):
  float* xg  = big;              // [8][1024][1024]    (8M)
  float* Hg  = big + 8*M1;       // [8][1024][4096]    (32M)
  float* Yg4 = big + 40*M1;      // [4][8][1024][1024] (32M)

  embed_k<<<dim3(1024), dim3(256), 0, stream>>>(sem, embt, bos, x);

  for (int i = 0; i < 2; ++i){
    const long iM = (long)i * 1048576;
    const float *wq = sa_wq + iM, *bq = sa_bq + i*1024;
    const float *wk = sa_wk + iM, *bk = sa_bk + i*1024;
    const float *wv = sa_wv + iM, *bv = sa_bv + i*1024;
    const float *wo = sa_wo + iM, *bo = sa_bo + i*1024;
    const float *cq = ca_wq + iM, *cbq = ca_bq + i*1024;
    const float *cwk = ca_wk + iM;
    const float *cwv = ca_wv + iM, *cbv = ca_bv + i*1024;
    const float *cwo = ca_wo + iM, *cbo = ca_bo + i*1024;
    const float *rw = rw_ + (long)i*8192, *rb = rb_ + i*8;
    const float *w1 = w1_ + (long)i*33554432, *b1 = b1_ + (long)i*32768;
    const float *w2 = w2_ + (long)i*33554432, *b2 = b2_ + (long)i*8192;

    // ---- self-attention ----
    gemm_k<64,64,false,1,true,3><<<dim3(16,16,3),dim3(256),0,stream>>>(
        x, wq, wk, wv, bq, bk, bv, nullptr, Qb,
        1024,1024,1024, 1,1024,0, 0,0,1048576, 0, 1.0f, nullptr, 1, 0);
    sattn_k<<<dim3(256),dim3(64),0,stream>>>(Qb, Kb, Vb, Ob);
    gemm_k<64,64,false,3,false,3><<<dim3(16,16,1),dim3(256),0,stream>>>(
        Ob, wo, nullptr,nullptr, bo, nullptr,nullptr, x, tmp,
        1024,1024,1024, 1,1024,0, 0,0,0, 0, 1.0f, nullptr, 1, 0);
    ln_k<<<dim3(1024),dim3(256),0,stream>>>(tmp, ln1g + i*1024, ln1b + i*1024, x, nullptr);

    // ---- cross-attention (restructured: no K/V projection of encoder) ----
    gemm_k<64,64,false,1,false,3><<<dim3(16,16,1),dim3(256),0,stream>>>(
        x, cq, nullptr,nullptr, cbq, nullptr,nullptr, nullptr, Qb,
        1024,1024,1024, 1,1024,0, 0,0,0, 0, 1.0f, nullptr, 1, 0);
    // Aca[h][t][n] = 0.125 * Q_h[t,:] @ cwk_h^T   (z = head)
    gemm_k<128,128,true,0,false,3><<<dim3(8,8,16),dim3(256),0,stream>>>(
        Qb, cwk, nullptr,nullptr, nullptr, nullptr,nullptr, nullptr, Aca,
        64,1024,1024, 1,1024,0, 64,64,1048576, 0, 0.125f, nullptr, 1, 0);
    // S[b][h*4+q][key] = Aca row . enc[b,key,:]   (z = batch, A rows remapped)
    gemm_k<64,128,true,0,false,3><<<dim3(4,1,256),dim3(256),0,stream>>>(
        Aca, enc, nullptr,nullptr, nullptr, nullptr,nullptr, nullptr, S,
        1024,1024,512, 4,1048576,1024, 4096,524288,32768, 0, 1.0f, nullptr, 1, 0);
    // Op[b][h*4+q][d] = softmax_row(S) @ enc[b]   (softmax fused: SMAX=true)
    gemm_k<64,128,false,0,false,3,true><<<dim3(8,1,256),dim3(256),0,stream>>>(
        S, enc, nullptr,nullptr, nullptr, nullptr,nullptr, nullptr, Op,
        512,1024,1024, 1,512,0, 32768,524288,65536, 0, 1.0f, nullptr, 1, 0);
    // Ob[t][h*64+n] = Op row @ cwv_h + cbv_h   (z = head, A rows remapped)
    gemm_k<64,64,false,1,false,3><<<dim3(1,16,16),dim3(256),0,stream>>>(
        Op, cwv, nullptr,nullptr, cbv, nullptr,nullptr, nullptr, Ob,
        1024,1024,1024, 4,65536,1024, 4096,64,64, 64, 1.0f, nullptr, 1, 0);
    gemm_k<64,64,false,3,false,3><<<dim3(16,16,1),dim3(256),0,stream>>>(
        Ob, cwo, nullptr,nullptr, cbo, nullptr,nullptr, x, tmp,
        1024,1024,1024, 1,1024,0, 0,0,0, 0, 1.0f, nullptr, 1, 0);
    // ln2 also zeroes the MoE counters (replaces hipMemsetAsync)
    ln_k<<<dim3(1024),dim3(256),0,stream>>>(tmp, ln2g + i*1024, ln2b + i*1024, x, cnt);

    // ---- MoE: top-2 sparse, experts batched over z; G2 split-K=4; BM=64 ----
    // Layer 1 feeds the layer-2 router -> fp32-accurate (NMFMA=3).
    // Layer 2 has no router downstream -> single rounded-bf16 MFMA (NMFMA=1).
    router_gather_k<<<dim3(1024),dim3(64),0,stream>>>(x, rw, rb, cnt, gw, sg, xg);
    if (i == 0){
      gemm_k<64,128,false,5,false,3><<<dim3(32,16,8),dim3(256),0,stream>>>(
          xg, w1, nullptr,nullptr, b1, nullptr,nullptr, nullptr, Hg,
          1024,4096,4096, 1,1024,0, 1048576,4194304,4194304, 4096, 1.0f, cnt, 1, 0);
      gemm_k<64,128,false,0,false,3><<<dim3(8,16,32),dim3(256),0,stream>>>(
          Hg, w2, nullptr,nullptr, nullptr, nullptr,nullptr, nullptr, Yg4,
          1024,1024,1024, 1,4096,0, 4194304,4194304,1048576, 0, 1.0f, cnt, 4, 8388608);
    } else {
      gemm_k<64,128,false,5,false,1><<<dim3(32,16,8),dim3(256),0,stream>>>(
          xg, w1, nullptr,nullptr, b1, nullptr,nullptr, nullptr, Hg,
          1024,4096,4096, 1,1024,0, 1048576,4194304,4194304, 4096, 1.0f, cnt, 1, 0);
      gemm_k<64,128,false,0,false,1><<<dim3(8,16,32),dim3(256),0,stream>>>(
          Hg, w2, nullptr,nullptr, nullptr, nullptr,nullptr, nullptr, Yg4,
          1024,1024,1024, 1,4096,0, 4194304,4194304,1048576, 0, 1.0f, cnt, 4, 8388608);
    }
    moe_ln_k<<<dim3(1024),dim3(256),0,stream>>>(x, Yg4, gw, sg, b2,
                                                ln3g + i*1024, ln3b + i*1024, x);
  }

  // ---- final LN + logits (terminal -> NMFMA=1, BM=64) ----
  ln_k<<<dim3(1024),dim3(256),0,stream>>>(x, lnfg, lnfb, tmp, nullptr);
  gemm_k<64,128,false,1,false,1><<<dim3(64,4,3),dim3(256),0,stream>>>(
      tmp, outw, nullptr,nullptr, outb, nullptr,nullptr, nullptr, logits,
      1024,8192,24576, 1,4096,0, 1024,8388608,8192, 8192, 1.0f, nullptr, 1, 0);
}

// Round 11
// 1645.457 us; speedup vs baseline: 1.1472x; 1.1472x over previous
//
#include <hip/hip_runtime.h>
#include <math.h>

typedef __attribute__((ext_vector_type(4))) float f32x4;
typedef __attribute__((ext_vector_type(8))) short s16x8;

__device__ __forceinline__ unsigned short f2bf(float f){
  union { float f; unsigned u; } v; v.f = f;
  return (unsigned short)((v.u + 0x7fffu + ((v.u >> 16) & 1u)) >> 16);
}
__device__ __forceinline__ float bf2f(unsigned short h){
  union { unsigned u; float f; } v; v.u = ((unsigned)h) << 16;
  return v.f;
}
// split v into hi (truncated bf16) + lo (rounded bf16 of remainder); hi+lo ~ v (rel err ~2^-16)
struct HL { short hi, lo; };
__device__ __forceinline__ HL split2(float v){
  union { float f; unsigned u; } c; c.f = v;
  unsigned short h = (unsigned short)(c.u >> 16);
  HL r; r.hi = (short)h; r.lo = (short)f2bf(v - bf2f(h));
  return r;
}
__device__ __forceinline__ void mk8(const f32x4& v0, const f32x4& v1, s16x8& hi, s16x8& lo){
  HL h;
  h = split2(v0.x); hi[0]=h.hi; lo[0]=h.lo;
  h = split2(v0.y); hi[1]=h.hi; lo[1]=h.lo;
  h = split2(v0.z); hi[2]=h.hi; lo[2]=h.lo;
  h = split2(v0.w); hi[3]=h.hi; lo[3]=h.lo;
  h = split2(v1.x); hi[4]=h.hi; lo[4]=h.lo;
  h = split2(v1.y); hi[5]=h.hi; lo[5]=h.lo;
  h = split2(v1.z); hi[6]=h.hi; lo[6]=h.lo;
  h = split2(v1.w); hi[7]=h.hi; lo[7]=h.lo;
}
__device__ __forceinline__ void mk8r(const f32x4& v0, const f32x4& v1, s16x8& hi){
  hi[0]=(short)f2bf(v0.x); hi[1]=(short)f2bf(v0.y);
  hi[2]=(short)f2bf(v0.z); hi[3]=(short)f2bf(v0.w);
  hi[4]=(short)f2bf(v1.x); hi[5]=(short)f2bf(v1.y);
  hi[6]=(short)f2bf(v1.z); hi[7]=(short)f2bf(v1.w);
}

// ---------------------------------------------------------------------------
// Split-bf16 MFMA GEMM, reg-double-buffered, optional split-K.
// NMFMA=3: fp32-accurate (hi/lo planes, 3 MFMA). NMFMA=1: rounded bf16, 1 MFMA
// (only for GEMMs with no routing decision downstream).
// Conflict-free kg-major LDS layout (granule (row,kg) at (row>>4)*512+kg*128+(row&15)*8).
//   z decomposes as (e, s): e = z/kspl, s = z%kspl; k-range = [s*K, (s+1)*K)
//   A row ptr = Ap + (gm/rdiv)*rs1 + (gm%rdiv)*rs2 + e*zsa + s*K + k
//   B (BT=0)  = Bp + e*zsb + (s*K + k)*ldb + gn
//   B (BT=1)  = Bp + e*zsb + gn*ldb + s*K + k
//   C index   = e*zsc + s*zscs + gm*ldc + gn
// EPI bits: 1=bias  2=+resid  4=gelu(exact)
// QKV3: e in {0,1,2} selects (Bp,bias)/(Bp1,bias1)/(Bp2,bias2)
// rowlim: per-e row count; blocks with blockM >= rowlim[e] exit (sparse MoE).
// ---------------------------------------------------------------------------
template<int BM, int BN, bool BT, int EPI, bool QKV3, int NMFMA>
__global__ __launch_bounds__(256)
void gemm_k(const float* __restrict__ Ap, const float* __restrict__ Bp,
            const float* __restrict__ Bp1, const float* __restrict__ Bp2,
            const float* __restrict__ bias, const float* __restrict__ bias1,
            const float* __restrict__ bias2,
            const float* __restrict__ resid, float* __restrict__ Cp,
            int K, int ldb, int ldc,
            int rdiv, long rs1, long rs2, long zsa, long zsb, long zsc, int zbias,
            float alpha, const int* __restrict__ rowlim, int kspl, long zscs)
{
  const int z = blockIdx.z;
  const int e = z / kspl, sps = z - e*kspl;
  const long kbeg = (long)sps * K;
  if (rowlim && (long)blockIdx.y * BM >= (long)rowlim[e]) return;

  const float* Bsel = Bp; const float* bsel = bias;
  if constexpr (QKV3){
    if (e == 1){ Bsel = Bp1; bsel = bias1; }
    else if (e == 2){ Bsel = Bp2; bsel = bias2; }
  }

  constexpr int NGA = BM/64;
  constexpr int NGB = BN/64;
  constexpr int LOG2BN = (BN == 128 ? 7 : 6);
  constexpr int PL = (NMFMA == 3 ? 2 : 1);

  __shared__ short As[PL][BM*32];
  __shared__ short Bs[PL][BN*32];

  const int tid  = threadIdx.x;
  const int lane = tid & 63;
  const int wid  = tid >> 6;
  const int wr   = wid >> 1, wc = wid & 1;
  constexpr int WM = BM/2, WN = BN/2;
  constexpr int MR = WM/16, NR = WN/16;

  const long blockM = (long)blockIdx.y * BM;
  const long blockN = (long)blockIdx.x * BN;

  long aoffG[NGA]; int aoffL[NGA];
#pragma unroll
  for (int i = 0; i < NGA; ++i){
    int g = i*256 + tid;
    int row = g >> 2, kg = g & 3;
    long gm = blockM + row;
    aoffG[i] = (gm / rdiv) * rs1 + (gm % rdiv) * rs2 + (long)e * zsa + kbeg + kg*8;
    aoffL[i] = (row >> 4)*512 + kg*128 + (row & 15)*8;
  }
  long boffG[NGB]; int boffL[NGB]; int bkg[NGB];
#pragma unroll
  for (int i = 0; i < NGB; ++i){
    int g = i*256 + tid;
    if constexpr (BT){
      int row = g >> 2, kg = g & 3;
      boffG[i] = (long)e * zsb + (blockN + row) * (long)ldb + kbeg + kg*8;
      boffL[i] = (row >> 4)*512 + kg*128 + (row & 15)*8;
      bkg[i] = 0;
    } else {
      int n = g & (BN-1), kg = g >> LOG2BN;
      boffG[i] = (long)e * zsb + blockN + n;
      bkg[i] = kg;
      boffL[i] = (n >> 4)*512 + kg*128 + (n & 15)*8;
    }
  }

  f32x4 acc[MR][NR];
#pragma unroll
  for (int m = 0; m < MR; ++m)
#pragma unroll
    for (int n = 0; n < NR; ++n)
      acc[m][n] = (f32x4){0.f, 0.f, 0.f, 0.f};

  const int lrow = lane & 15;
  const int kg   = lane >> 4;

  auto loadA = [&](int kk, f32x4 (*a)[2]){
#pragma unroll
    for (int i = 0; i < NGA; ++i){
      a[i][0] = *(const f32x4*)(Ap + aoffG[i] + kk);
      a[i][1] = *(const f32x4*)(Ap + aoffG[i] + kk + 4);
    }
  };
  auto loadB = [&](int kk, f32x4 (*b)[2]){
#pragma unroll
    for (int i = 0; i < NGB; ++i){
      if constexpr (BT){
        b[i][0] = *(const f32x4*)(Bsel + boffG[i] + kk);
        b[i][1] = *(const f32x4*)(Bsel + boffG[i] + kk + 4);
      } else {
        long kb = kbeg + kk + bkg[i]*8;
#pragma unroll
        for (int j = 0; j < 4; ++j){
          b[i][0][j] = Bsel[boffG[i] + (kb + j)     * (long)ldb];
          b[i][1][j] = Bsel[boffG[i] + (kb + 4 + j) * (long)ldb];
        }
      }
    }
  };
  auto process = [&](f32x4 (*a)[2], f32x4 (*b)[2]){
    __syncthreads();
#pragma unroll
    for (int i = 0; i < NGA; ++i){
      if constexpr (NMFMA == 3){
        s16x8 hi, lo; mk8(a[i][0], a[i][1], hi, lo);
        *(s16x8*)&As[0][aoffL[i]] = hi;
        *(s16x8*)&As[1][aoffL[i]] = lo;
      } else {
        s16x8 hi; mk8r(a[i][0], a[i][1], hi);
        *(s16x8*)&As[0][aoffL[i]] = hi;
      }
    }
#pragma unroll
    for (int i = 0; i < NGB; ++i){
      if constexpr (NMFMA == 3){
        s16x8 hi, lo; mk8(b[i][0], b[i][1], hi, lo);
        *(s16x8*)&Bs[0][boffL[i]] = hi;
        *(s16x8*)&Bs[1][boffL[i]] = lo;
      } else {
        s16x8 hi; mk8r(b[i][0], b[i][1], hi);
        *(s16x8*)&Bs[0][boffL[i]] = hi;
      }
    }
    __syncthreads();

    s16x8 afh[MR], afl[MR], bfh[NR], bfl[NR];
#pragma unroll
    for (int m = 0; m < MR; ++m){
      int off = (wr*MR + m)*512 + kg*128 + lrow*8;
      afh[m] = *(const s16x8*)&As[0][off];
      if constexpr (NMFMA == 3) afl[m] = *(const s16x8*)&As[1][off];
    }
#pragma unroll
    for (int n = 0; n < NR; ++n){
      int off = (wc*NR + n)*512 + kg*128 + lrow*8;
      bfh[n] = *(const s16x8*)&Bs[0][off];
      if constexpr (NMFMA == 3) bfl[n] = *(const s16x8*)&Bs[1][off];
    }
#pragma unroll
    for (int m = 0; m < MR; ++m)
#pragma unroll
      for (int n = 0; n < NR; ++n){
        acc[m][n] = __builtin_amdgcn_mfma_f32_16x16x32_bf16(afh[m], bfh[n], acc[m][n], 0, 0, 0);
        if constexpr (NMFMA == 3){
          acc[m][n] = __builtin_amdgcn_mfma_f32_16x16x32_bf16(afl[m], bfh[n], acc[m][n], 0, 0, 0);
          acc[m][n] = __builtin_amdgcn_mfma_f32_16x16x32_bf16(afh[m], bfl[n], acc[m][n], 0, 0, 0);
        }
      }
  };

  f32x4 a0[NGA][2], a1[NGA][2], b0[NGB][2], b1[NGB][2];
  loadA(0, a0); loadB(0, b0);
  for (int k0 = 0; k0 < K; k0 += 64){
    loadA(k0 + 32, a1); loadB(k0 + 32, b1);
    process(a0, b0);
    if (k0 + 64 < K){ loadA(k0 + 64, a0); loadB(k0 + 64, b0); }
    process(a1, b1);
  }

#pragma unroll
  for (int n = 0; n < NR; ++n){
    long gn = blockN + wc*WN + n*16 + lrow;
    float bv = 0.f;
    if constexpr ((EPI & 1) != 0) bv = bsel[(long)e * zbias + gn];
#pragma unroll
    for (int m = 0; m < MR; ++m){
#pragma unroll
      for (int j = 0; j < 4; ++j){
        long gm = blockM + wr*WM + m*16 + kg*4 + j;
        long cidx = (long)e * zsc + sps * zscs + gm * (long)ldc + gn;
        float v = acc[m][n][j] * alpha + bv;
        if constexpr ((EPI & 2) != 0) v += resid[cidx];
        if constexpr ((EPI & 4) != 0) v = 0.5f * v * (1.0f + erff(v * 0.70710678f));
        Cp[cidx] = v;
      }
    }
  }
}

// ---------------- embedding: x[b,0]=bos, x[b,1+r]=emb_tables[r, ids[b,r]] ----
__global__ __launch_bounds__(256)
void embed_k(const int* __restrict__ ids, const float* __restrict__ embt,
             const float* __restrict__ bos, float* __restrict__ x)
{
  int t = blockIdx.x;
  int b = t >> 2, q = t & 3;
  const float* src;
  if (q == 0) src = bos;
  else {
    int r = q - 1;
    long id = ids[b*3 + r];
    src = embt + ((long)r * 8192 + id) * 1024;
  }
  f32x4 v = *(const f32x4*)(src + threadIdx.x * 4);
  *(f32x4*)(x + (long)t * 1024 + threadIdx.x * 4) = v;
}

// ---------------- tiny causal self-attn over T=4 ----------------
__global__ __launch_bounds__(64)
void sattn_k(const float* __restrict__ Q, const float* __restrict__ Kk,
             const float* __restrict__ V, float* __restrict__ O)
{
  int tid = blockIdx.x * 64 + threadIdx.x;
  int q = tid & 3, h = (tid >> 2) & 15;
  long b = tid >> 6;
  long t = b*4 + q;
  const float* qp = Q + t*1024 + h*64;
  float s[4]; float mx = -1e30f;
  for (int k = 0; k <= q; ++k){
    const float* kp = Kk + (b*4 + k)*1024 + h*64;
    float a = 0.f;
#pragma unroll
    for (int d = 0; d < 64; ++d) a += qp[d] * kp[d];
    s[k] = a * 0.125f; mx = fmaxf(mx, s[k]);
  }
  float den = 0.f;
  for (int k = 0; k <= q; ++k){ s[k] = expf(s[k] - mx); den += s[k]; }
  float inv = 1.f / den;
  float* op = O + t*1024 + h*64;
  for (int d = 0; d < 64; ++d){
    float a = 0.f;
    for (int k = 0; k <= q; ++k) a += s[k] * V[(b*4 + k)*1024 + h*64 + d];
    op[d] = a * inv;
  }
}

// ---------------- LayerNorm (optionally zeroes an 8-int counter array) -------
__global__ __launch_bounds__(256)
void ln_k(const float* __restrict__ in, const float* __restrict__ g,
          const float* __restrict__ b, float* __restrict__ out,
          int* __restrict__ zero8)
{
  __shared__ float red[8];
  long row = blockIdx.x;
  int tid = threadIdx.x, lane = tid & 63, wid = tid >> 6;
  if (zero8 && blockIdx.x == 0 && tid < 8) zero8[tid] = 0;
  f32x4 v = ((const f32x4*)(in + row*1024))[tid];
  float s  = v.x + v.y + v.z + v.w;
  float s2 = v.x*v.x + v.y*v.y + v.z*v.z + v.w*v.w;
  for (int o = 32; o; o >>= 1){ s += __shfl_down(s, o); s2 += __shfl_down(s2, o); }
  if (!lane){ red[wid] = s; red[4 + wid] = s2; }
  __syncthreads();
  if (tid == 0){
    float S = red[0]+red[1]+red[2]+red[3], S2 = red[4]+red[5]+red[6]+red[7];
    float m = S * (1.f/1024.f);
    float var = S2 * (1.f/1024.f) - m*m;
    red[0] = m; red[1] = 1.0f / sqrtf(var + 1e-5f);
  }
  __syncthreads();
  float m = red[0], r = red[1];
  f32x4 gv = ((const f32x4*)g)[tid], bv = ((const f32x4*)b)[tid];
  f32x4 o;
  o.x = (v.x - m)*r*gv.x + bv.x; o.y = (v.y - m)*r*gv.y + bv.y;
  o.z = (v.z - m)*r*gv.z + bv.z; o.w = (v.w - m)*r*gv.w + bv.w;
  ((f32x4*)(out + row*1024))[tid] = o;
}

// ------ MoE combine: sum 4 split-K partials + expert bias, gate, resid, LN ----
__global__ __launch_bounds__(256)
void moe_ln_k(const float* __restrict__ x, const float* __restrict__ Yg4,
              const float* __restrict__ gwp, const int* __restrict__ sg,
              const float* __restrict__ b2,
              const float* __restrict__ g, const float* __restrict__ b,
              float* __restrict__ out)
{
  __shared__ float red[8];
  long t = blockIdx.x;
  int tid = threadIdx.x, lane = tid & 63, wid = tid >> 6;
  float w0 = gwp[t*2], w1 = gwp[t*2 + 1];
  long r0 = sg[t*2], r1 = sg[t*2 + 1];
  long e0 = r0 >> 10, e1 = r1 >> 10;
  const long SP = 8388608;
  f32x4 y0 = ((const f32x4*)(Yg4 + 0*SP + r0*1024))[tid];
  f32x4 y1 = ((const f32x4*)(Yg4 + 0*SP + r1*1024))[tid];
#pragma unroll
  for (int s = 1; s < 4; ++s){
    y0 = y0 + ((const f32x4*)(Yg4 + s*SP + r0*1024))[tid];
    y1 = y1 + ((const f32x4*)(Yg4 + s*SP + r1*1024))[tid];
  }
  y0 = y0 + ((const f32x4*)(b2 + e0*1024))[tid];
  y1 = y1 + ((const f32x4*)(b2 + e1*1024))[tid];
  f32x4 v = ((const f32x4*)(x + t*1024))[tid];
  v = v + y0*w0 + y1*w1;
  float s  = v.x + v.y + v.z + v.w;
  float s2 = v.x*v.x + v.y*v.y + v.z*v.z + v.w*v.w;
  for (int o = 32; o; o >>= 1){ s += __shfl_down(s, o); s2 += __shfl_down(s2, o); }
  if (!lane){ red[wid] = s; red[4 + wid] = s2; }
  __syncthreads();
  if (tid == 0){
    float S = red[0]+red[1]+red[2]+red[3], S2 = red[4]+red[5]+red[6]+red[7];
    float m = S * (1.f/1024.f);
    float var = S2 * (1.f/1024.f) - m*m;
    red[0] = m; red[1] = 1.0f / sqrtf(var + 1e-5f);
  }
  __syncthreads();
  float m = red[0], r = red[1];
  f32x4 gv = ((const f32x4*)g)[tid], bv = ((const f32x4*)b)[tid];
  f32x4 o;
  o.x = (v.x - m)*r*gv.x + bv.x; o.y = (v.y - m)*r*gv.y + bv.y;
  o.z = (v.z - m)*r*gv.z + bv.z; o.w = (v.w - m)*r*gv.w + bv.w;
  ((f32x4*)(out + t*1024))[tid] = o;
}

// ---------------- fused router + scatter + gather ----------------
__global__ __launch_bounds__(64)
void router_gather_k(const float* __restrict__ x, const float* __restrict__ rw,
                     const float* __restrict__ rb, int* __restrict__ cnt,
                     float* __restrict__ gw, int* __restrict__ sg,
                     float* __restrict__ xg)
{
  long t = blockIdx.x;
  int lane = threadIdx.x;
  __shared__ int ssl[2];
  float acc[8] = {0,0,0,0,0,0,0,0};
  const float* xp = x + t*1024;
  for (int i = 0; i < 16; ++i){
    float xv = xp[lane + i*64];
    const float* w = rw + (long)(lane + i*64) * 8;
#pragma unroll
    for (int e = 0; e < 8; ++e) acc[e] += xv * w[e];
  }
#pragma unroll
  for (int e = 0; e < 8; ++e)
    for (int o = 32; o; o >>= 1) acc[e] += __shfl_down(acc[e], o);
  if (lane == 0){
    float lg[8]; float mx = -1e30f;
#pragma unroll
    for (int e = 0; e < 8; ++e){ lg[e] = acc[e] + rb[e]; mx = fmaxf(mx, lg[e]); }
    float ssum = 0.f;
#pragma unroll
    for (int e = 0; e < 8; ++e){ lg[e] = expf(lg[e] - mx); ssum += lg[e]; }
    float inv = 1.f / ssum;
#pragma unroll
    for (int e = 0; e < 8; ++e) lg[e] *= inv;
    int i0 = 0; float p0 = lg[0];
#pragma unroll
    for (int e = 1; e < 8; ++e) if (lg[e] > p0){ p0 = lg[e]; i0 = e; }
    int i1 = -1; float p1 = -1e30f;
#pragma unroll
    for (int e = 0; e < 8; ++e) if (e != i0 && lg[e] > p1){ p1 = lg[e]; i1 = e; }
    float w0 = 1.f / (1.f + expf(p1 - p0));
    int s0 = atomicAdd(&cnt[i0], 1);
    int s1 = atomicAdd(&cnt[i1], 1);
    int r0 = i0*1024 + s0, r1 = i1*1024 + s1;
    gw[t*2] = w0; gw[t*2 + 1] = 1.f - w0;
    sg[t*2] = r0; sg[t*2 + 1] = r1;
    ssl[0] = r0; ssl[1] = r1;
  }
  __syncthreads();
  const f32x4* xp4 = (const f32x4*)(x + t*1024);
#pragma unroll
  for (int r = 0; r < 2; ++r){
    f32x4* dp = (f32x4*)(xg + (long)ssl[r]*1024);
#pragma unroll
    for (int i = 0; i < 4; ++i) dp[lane + i*64] = xp4[lane + i*64];
  }
}

// ---------------- cross-attn softmax: rows of 512, fp32 in-place --------------
__global__ __launch_bounds__(256)
void casm_k(float* __restrict__ S)
{
  long row = (long)blockIdx.x * 4 + (threadIdx.x >> 6);
  int lane = threadIdx.x & 63;
  float* p = S + row * 512;
  f32x4 a = *(const f32x4*)(p + lane*4);
  f32x4 c = *(const f32x4*)(p + 256 + lane*4);
  float mx = fmaxf(fmaxf(fmaxf(a.x, a.y), fmaxf(a.z, a.w)),
                   fmaxf(fmaxf(c.x, c.y), fmaxf(c.z, c.w)));
  for (int o = 32; o; o >>= 1) mx = fmaxf(mx, __shfl_xor(mx, o));
  a.x = expf(a.x - mx); a.y = expf(a.y - mx); a.z = expf(a.z - mx); a.w = expf(a.w - mx);
  c.x = expf(c.x - mx); c.y = expf(c.y - mx); c.z = expf(c.z - mx); c.w = expf(c.w - mx);
  float sm = a.x+a.y+a.z+a.w + c.x+c.y+c.z+c.w;
  for (int o = 32; o; o >>= 1) sm += __shfl_xor(sm, o);
  float inv = 1.f / sm;
  *(f32x4*)(p + lane*4) = a * inv;
  *(f32x4*)(p + 256 + lane*4) = c * inv;
}

// ===========================================================================
extern "C" void kernel_launch(void* const* d_in, const int* in_sizes, int n_in,
                              void* d_out, int out_size, void* d_ws, size_t ws_size,
                              hipStream_t stream)
{
  (void)in_sizes; (void)n_in; (void)out_size; (void)ws_size;
  const int*   sem  = (const int*)  d_in[0];
  const float* enc  = (const float*)d_in[1];
  const float* embt = (const float*)d_in[2];
  const float* bos  = (const float*)d_in[3];
  const float* sa_wq = (const float*)d_in[4];  const float* sa_bq = (const float*)d_in[5];
  const float* sa_wk = (const float*)d_in[6];  const float* sa_bk = (const float*)d_in[7];
  const float* sa_wv = (const float*)d_in[8];  const float* sa_bv = (const float*)d_in[9];
  const float* sa_wo = (const float*)d_in[10]; const float* sa_bo = (const float*)d_in[11];
  const float* ca_wq = (const float*)d_in[12]; const float* ca_bq = (const float*)d_in[13];
  const float* ca_wk = (const float*)d_in[14]; /* ca_bk d_in[15]: softmax-invariant, dropped */
  const float* ca_wv = (const float*)d_in[16]; const float* ca_bv = (const float*)d_in[17];
  const float* ca_wo = (const float*)d_in[18]; const float* ca_bo = (const float*)d_in[19];
  const float* rw_   = (const float*)d_in[20]; const float* rb_   = (const float*)d_in[21];
  const float* w1_   = (const float*)d_in[22]; const float* b1_   = (const float*)d_in[23];
  const float* w2_   = (const float*)d_in[24]; const float* b2_   = (const float*)d_in[25];
  const float* ln1g = (const float*)d_in[26];  const float* ln1b = (const float*)d_in[27];
  const float* ln2g = (const float*)d_in[28];  const float* ln2b = (const float*)d_in[29];
  const float* ln3g = (const float*)d_in[30];  const float* ln3b = (const float*)d_in[31];
  const float* lnfg = (const float*)d_in[32];  const float* lnfb = (const float*)d_in[33];
  const float* outw = (const float*)d_in[34];  const float* outb = (const float*)d_in[35];
  float* logits = (float*)d_out;

  // ---- workspace carve (floats). head 6M + big 72M ~= 312 MiB ----
  float* ws = (float*)d_ws;
  const long M1 = 1l << 20;
  float* x   = ws;
  float* Qb  = ws + 1*M1;
  float* Kb  = ws + 2*M1;
  float* Vb  = ws + 3*M1;
  float* Ob  = ws + 4*M1;
  float* tmp = ws + 5*M1;
  float* gw  = ws + 6*M1;
  int*   cnt = (int*)(ws + 6*M1 + 4096);
  int*   sg  = (int*)(ws + 6*M1 + 4352);
  float* big = ws + 6*M1 + 8192;
  // cross-attn phase:
  float* Aca = big;              // [16][1024][1024] f32 (16M)
  float* S   = big + 16*M1;      // [256][64][512]   f32 (8M); softmax in-place
  float* Op  = big;              // [256][64][1024]  f32 (16M) — reuses Aca (dead)
  // MoE phase (CA region dead):
  float* xg  = big;              // [8][1024][1024]    (8M)
  float* Hg  = big + 8*M1;       // [8][1024][4096]    (32M)
  float* Yg4 = big + 40*M1;      // [4][8][1024][1024] (32M)

  embed_k<<<dim3(1024), dim3(256), 0, stream>>>(sem, embt, bos, x);

  for (int i = 0; i < 2; ++i){
    const long iM = (long)i * 1048576;
    const float *wq = sa_wq + iM, *bq = sa_bq + i*1024;
    const float *wk = sa_wk + iM, *bk = sa_bk + i*1024;
    const float *wv = sa_wv + iM, *bv = sa_bv + i*1024;
    const float *wo = sa_wo + iM, *bo = sa_bo + i*1024;
    const float *cq = ca_wq + iM, *cbq = ca_bq + i*1024;
    const float *cwk = ca_wk + iM;
    const float *cwv = ca_wv + iM, *cbv = ca_bv + i*1024;
    const float *cwo = ca_wo + iM, *cbo = ca_bo + i*1024;
    const float *rw = rw_ + (long)i*8192, *rb = rb_ + i*8;
    const float *w1 = w1_ + (long)i*33554432, *b1 = b1_ + (long)i*32768;
    const float *w2 = w2_ + (long)i*33554432, *b2 = b2_ + (long)i*8192;

    // ---- self-attention ----
    gemm_k<64,64,false,1,true,3><<<dim3(16,16,3),dim3(256),0,stream>>>(
        x, wq, wk, wv, bq, bk, bv, nullptr, Qb,
        1024,1024,1024, 1,1024,0, 0,0,1048576, 0, 1.0f, nullptr, 1, 0);
    sattn_k<<<dim3(256),dim3(64),0,stream>>>(Qb, Kb, Vb, Ob);
    gemm_k<64,64,false,3,false,3><<<dim3(16,16,1),dim3(256),0,stream>>>(
        Ob, wo, nullptr,nullptr, bo, nullptr,nullptr, x, tmp,
        1024,1024,1024, 1,1024,0, 0,0,0, 0, 1.0f, nullptr, 1, 0);
    ln_k<<<dim3(1024),dim3(256),0,stream>>>(tmp, ln1g + i*1024, ln1b + i*1024, x, nullptr);

    // ---- cross-attention (restructured: no K/V projection of encoder) ----
    gemm_k<64,64,false,1,false,3><<<dim3(16,16,1),dim3(256),0,stream>>>(
        x, cq, nullptr,nullptr, cbq, nullptr,nullptr, nullptr, Qb,
        1024,1024,1024, 1,1024,0, 0,0,0, 0, 1.0f, nullptr, 1, 0);
    // Aca[h][t][n] = 0.125 * Q_h[t,:] @ cwk_h^T   (z = head)
    gemm_k<128,128,true,0,false,3><<<dim3(8,8,16),dim3(256),0,stream>>>(
        Qb, cwk, nullptr,nullptr, nullptr, nullptr,nullptr, nullptr, Aca,
        64,1024,1024, 1,1024,0, 64,64,1048576, 0, 0.125f, nullptr, 1, 0);
    // S[b][h*4+q][key] = Aca row . enc[b,key,:]   (z = batch, A rows remapped)
    gemm_k<64,128,true,0,false,3><<<dim3(4,1,256),dim3(256),0,stream>>>(
        Aca, enc, nullptr,nullptr, nullptr, nullptr,nullptr, nullptr, S,
        1024,1024,512, 4,1048576,1024, 4096,524288,32768, 0, 1.0f, nullptr, 1, 0);
    casm_k<<<dim3(4096),dim3(256),0,stream>>>(S);
    // Op[b][h*4+q][d] = P row @ enc[b]
    gemm_k<64,128,false,0,false,3><<<dim3(8,1,256),dim3(256),0,stream>>>(
        S, enc, nullptr,nullptr, nullptr, nullptr,nullptr, nullptr, Op,
        512,1024,1024, 1,512,0, 32768,524288,65536, 0, 1.0f, nullptr, 1, 0);
    // Ob[t][h*64+n] = Op row @ cwv_h + cbv_h   (z = head, A rows remapped)
    gemm_k<64,64,false,1,false,3><<<dim3(1,16,16),dim3(256),0,stream>>>(
        Op, cwv, nullptr,nullptr, cbv, nullptr,nullptr, nullptr, Ob,
        1024,1024,1024, 4,65536,1024, 4096,64,64, 64, 1.0f, nullptr, 1, 0);
    gemm_k<64,64,false,3,false,3><<<dim3(16,16,1),dim3(256),0,stream>>>(
        Ob, cwo, nullptr,nullptr, cbo, nullptr,nullptr, x, tmp,
        1024,1024,1024, 1,1024,0, 0,0,0, 0, 1.0f, nullptr, 1, 0);
    // ln2 also zeroes the MoE counters (replaces hipMemsetAsync)
    ln_k<<<dim3(1024),dim3(256),0,stream>>>(tmp, ln2g + i*1024, ln2b + i*1024, x, cnt);

    // ---- MoE: top-2 sparse, experts batched over z; G2 split-K=4; BM=64 ----
    // Layer 1 feeds the layer-2 router -> fp32-accurate (NMFMA=3).
    // Layer 2 has no router downstream -> single rounded-bf16 MFMA (NMFMA=1).
    router_gather_k<<<dim3(1024),dim3(64),0,stream>>>(x, rw, rb, cnt, gw, sg, xg);
    if (i == 0){
      gemm_k<64,128,false,5,false,3><<<dim3(32,16,8),dim3(256),0,stream>>>(
          xg, w1, nullptr,nullptr, b1, nullptr,nullptr, nullptr, Hg,
          1024,4096,4096, 1,1024,0, 1048576,4194304,4194304, 4096, 1.0f, cnt, 1, 0);
      gemm_k<64,128,false,0,false,3><<<dim3(8,16,32),dim3(256),0,stream>>>(
          Hg, w2, nullptr,nullptr, nullptr, nullptr,nullptr, nullptr, Yg4,
          1024,1024,1024, 1,4096,0, 4194304,4194304,1048576, 0, 1.0f, cnt, 4, 8388608);
    } else {
      gemm_k<64,128,false,5,false,1><<<dim3(32,16,8),dim3(256),0,stream>>>(
          xg, w1, nullptr,nullptr, b1, nullptr,nullptr, nullptr, Hg,
          1024,4096,4096, 1,1024,0, 1048576,4194304,4194304, 4096, 1.0f, cnt, 1, 0);
      gemm_k<64,128,false,0,false,1><<<dim3(8,16,32),dim3(256),0,stream>>>(
          Hg, w2, nullptr,nullptr, nullptr, nullptr,nullptr, nullptr, Yg4,
          1024,1024,1024, 1,4096,0, 4194304,4194304,1048576, 0, 1.0f, cnt, 4, 8388608);
    }
    moe_ln_k<<<dim3(1024),dim3(256),0,stream>>>(x, Yg4, gw, sg, b2,
                                                ln3g + i*1024, ln3b + i*1024, x);
  }

  // ---- final LN + logits (terminal -> NMFMA=1, BM=64) ----
  ln_k<<<dim3(1024),dim3(256),0,stream>>>(x, lnfg, lnfb, tmp, nullptr);
  gemm_k<64,128,false,1,false,1><<<dim3(64,4,3),dim3(256),0,stream>>>(
      tmp, outw, nullptr,nullptr, outb, nullptr,nullptr, nullptr, logits,
      1024,8192,24576, 1,4096,0, 1024,8388608,8192, 8192, 1.0f, nullptr, 1, 0);
}